// Round 1
// baseline (341.931 us; speedup 1.0000x reference)
//
#include <hip/hip_runtime.h>

typedef __bf16 bf16x8 __attribute__((ext_vector_type(8)));
typedef float f32x4 __attribute__((ext_vector_type(4)));
typedef unsigned short us4 __attribute__((ext_vector_type(4)));

#define Q_LEN 1024
#define R_LEN 2048
#define BATCH 2
#define DM 1024
#define NH 16
#define DH 64
#define ND 1024

__device__ __forceinline__ unsigned short f2bf(float f) {
  unsigned int u = __builtin_bit_cast(unsigned int, f);
  u += 0x7fffu + ((u >> 16) & 1u);
  return (unsigned short)(u >> 16);
}
__device__ __forceinline__ float bf2f(unsigned short s) {
  unsigned int u = ((unsigned int)s) << 16;
  return __builtin_bit_cast(float, u);
}
__device__ __forceinline__ f32x4 mfma16(bf16x8 a, bf16x8 b, f32x4 c) {
  return __builtin_amdgcn_mfma_f32_16x16x32_bf16(a, b, c, 0, 0, 0);
}

// ---------------- cast f32 -> bf16 (vectorized) ----------------
__global__ __launch_bounds__(256) void cast_kernel(const float* __restrict__ in,
                                                   unsigned short* __restrict__ out, int n4) {
  int idx = blockIdx.x * 256 + threadIdx.x;
  if (idx < n4) {
    float4 v = ((const float4*)in)[idx];
    us4 o;
    o[0] = f2bf(v.x); o[1] = f2bf(v.y); o[2] = f2bf(v.z); o[3] = f2bf(v.w);
    *(us4*)&out[idx * 4] = o;
  }
}

// ---------------- transpose+cast weight [1024][1024] f32 -> [N][K] bf16 ----------------
__global__ __launch_bounds__(256) void transpose_cast(const float* __restrict__ in,
                                                      unsigned short* __restrict__ out) {
  __shared__ float t[32][33];
  int k0 = blockIdx.y * 32;
  int n0 = blockIdx.x * 32;
  int r = threadIdx.x >> 5;   // 0..7
  int c = threadIdx.x & 31;
#pragma unroll
  for (int s = 0; s < 4; ++s)
    t[r + s * 8][c] = in[(k0 + r + s * 8) * 1024 + n0 + c];
  __syncthreads();
#pragma unroll
  for (int s = 0; s < 4; ++s)
    out[(n0 + r + s * 8) * 1024 + k0 + c] = f2bf(t[c][r + s * 8]);
}

// ---------------- GEMM: C[M,N] = A[M,K] * Bt[N,K]^T (bf16 in) ----------------
template <int NOUT, bool F32OUT>
__global__ __launch_bounds__(256) void gemm_bt(
    const unsigned short* __restrict__ A, const unsigned short* __restrict__ Bt,
    int M, int N, int K,
    void* __restrict__ C0, const float* __restrict__ bias0,
    void* __restrict__ C1, const float* __restrict__ bias1,
    void* __restrict__ C2, const float* __restrict__ bias2) {
  __shared__ unsigned short sA[128][40];
  __shared__ unsigned short sB[128][40];
  const int tid = threadIdx.x, lane = tid & 63, w = tid >> 6;
  const int wm = w >> 1, wn = w & 1;
  const int g = lane >> 4, lc = lane & 15;
  const int m0 = blockIdx.y * 128, n0 = blockIdx.x * 128;
  f32x4 acc[4][4] = {};
  for (int kt = 0; kt < K; kt += 32) {
#pragma unroll
    for (int s = 0; s < 2; ++s) {
      int c = tid + 256 * s;
      int row = c >> 2, ko = (c & 3) * 8;
      *(uint4*)&sA[row][ko] = *(const uint4*)&A[(m0 + row) * K + kt + ko];
      *(uint4*)&sB[row][ko] = *(const uint4*)&Bt[(n0 + row) * K + kt + ko];
    }
    __syncthreads();
    bf16x8 af[4], bfr[4];
#pragma unroll
    for (int i = 0; i < 4; ++i) {
      af[i] = *(const bf16x8*)&sA[wm * 64 + i * 16 + lc][g * 8];
      bfr[i] = *(const bf16x8*)&sB[wn * 64 + i * 16 + lc][g * 8];
    }
#pragma unroll
    for (int mi = 0; mi < 4; ++mi)
#pragma unroll
      for (int ni = 0; ni < 4; ++ni)
        acc[mi][ni] = mfma16(af[mi], bfr[ni], acc[mi][ni]);
    __syncthreads();
  }
#pragma unroll
  for (int ni = 0; ni < 4; ++ni) {
    int col = n0 + wn * 64 + ni * 16 + lc;
    float bv0 = 0.f, bv1 = 0.f, bv2 = 0.f;
    if (NOUT >= 1 && bias0) bv0 = bias0[col];
    if (NOUT >= 2 && bias1) bv1 = bias1[col];
    if (NOUT >= 3 && bias2) bv2 = bias2[col];
#pragma unroll
    for (int mi = 0; mi < 4; ++mi) {
      int rowb = m0 + wm * 64 + mi * 16 + g * 4;
#pragma unroll
      for (int r = 0; r < 4; ++r) {
        float v = acc[mi][ni][r];
        int idx = (rowb + r) * N + col;
        if (F32OUT) {
          ((float*)C0)[idx] = v + bv0;
        } else {
          ((unsigned short*)C0)[idx] = f2bf(v + bv0);
          if (NOUT >= 2) ((unsigned short*)C1)[idx] = f2bf(v + bv1);
          if (NOUT >= 3) ((unsigned short*)C2)[idx] = f2bf(v + bv2);
        }
      }
    }
  }
}

// ---------------- V transpose: vh[(j*B+b)*ND + n*64+d] -> vT[(bn*64+d)*Q + j] ----------------
__global__ __launch_bounds__(256) void transpose_v(const unsigned short* __restrict__ vh,
                                                   unsigned short* __restrict__ vT) {
  __shared__ unsigned short t[64][65];
  const int bn = blockIdx.y, j0 = blockIdx.x * 64;
  const int b = bn >> 4, n = bn & 15;
  const int r = threadIdx.x >> 4;          // 0..15
  const int c4 = (threadIdx.x & 15) * 4;   // 0..60
#pragma unroll
  for (int s = 0; s < 4; ++s) {
    int j = r + s * 16;
    us4 v = *(const us4*)&vh[((j0 + j) * 2 + b) * 1024 + n * 64 + c4];
    t[j][c4 + 0] = v[0]; t[j][c4 + 1] = v[1]; t[j][c4 + 2] = v[2]; t[j][c4 + 3] = v[3];
  }
  __syncthreads();
#pragma unroll
  for (int s = 0; s < 4; ++s) {
    int d = r + s * 16;
    us4 v;
    v[0] = t[c4 + 0][d]; v[1] = t[c4 + 1][d]; v[2] = t[c4 + 2][d]; v[3] = t[c4 + 3][d];
    *(us4*)&vT[(bn * 64 + d) * 1024 + j0 + c4] = v;
  }
}

// ---------------- ef0/ef1: per (i,b,n) dot of qs row with seg_embed ----------------
__global__ __launch_bounds__(256) void ef_kernel(const unsigned short* __restrict__ qs,
                                                 const float* __restrict__ seg_embed,
                                                 float* __restrict__ ef0, float* __restrict__ ef1) {
  int gw = blockIdx.x * 4 + (threadIdx.x >> 6);
  int lane = threadIdx.x & 63;
  int n = gw & 15, ib = gw >> 4;  // ib = i*2+b
  int i = ib >> 1, b = ib & 1;
  float qv = bf2f(qs[ib * 1024 + n * 64 + lane]);
  float p0 = qv * seg_embed[n * 64 + lane];
  float p1 = qv * seg_embed[1024 + n * 64 + lane];
#pragma unroll
  for (int m = 1; m < 64; m <<= 1) {
    p0 += __shfl_xor(p0, m);
    p1 += __shfl_xor(p1, m);
  }
  if (lane == 0) {
    ef0[(b * 16 + n) * 1024 + i] = p0;
    ef1[(b * 16 + n) * 1024 + i] = p1;
  }
}

// ---------------- fused relative attention (flash-style) ----------------
__global__ __launch_bounds__(256) void attn_kernel(
    const unsigned short* __restrict__ qw, const unsigned short* __restrict__ qr,
    const unsigned short* __restrict__ kh, const unsigned short* __restrict__ krh,
    const unsigned short* __restrict__ vT,
    const float* __restrict__ ef0, const float* __restrict__ ef1,
    const unsigned char* __restrict__ seg, const float* __restrict__ mask,
    unsigned short* __restrict__ av) {
  __shared__ unsigned short sK[64][72];     // K tile  [j][d]  (Bt for ac)
  __shared__ unsigned short sKR[128][72];   // Kr band [jr][d] (Bt for bd)
  __shared__ unsigned short sVT[64][72];    // V^T     [d][j]  (Bt for pv)
  __shared__ unsigned short sBD[64][132];   // bd band, bf16 [i_loc][jr_loc]
  __shared__ unsigned short sP[4][16][72];  // per-wave P tile [i][j]

  const int tid = threadIdx.x, lane = tid & 63, w = tid >> 6;
  const int g = lane >> 4, lc = lane & 15;
  const int bn = blockIdx.y, b = bn >> 4, n = bn & 15;
  const int i0 = blockIdx.x * 64;

  // load Q fragments (rows of this wave, k split in two MFMA steps)
  bf16x8 fqw[2], fqr[2];
  const int qrow = i0 + w * 16 + lc;
#pragma unroll
  for (int ks = 0; ks < 2; ++ks) {
    int off = (qrow * 2 + b) * 1024 + n * 64 + ks * 32 + g * 8;
    fqw[ks] = *(const bf16x8*)&qw[off];
    fqr[ks] = *(const bf16x8*)&qr[off];
  }
  float ef0v[4], ef1v[4];
#pragma unroll
  for (int r = 0; r < 4; ++r) {
    int i = i0 + w * 16 + g * 4 + r;
    ef0v[r] = ef0[bn * 1024 + i];
    ef1v[r] = ef1[bn * 1024 + i];
  }
  float mrun[4], lsum[4];
  f32x4 accO[4] = {};
#pragma unroll
  for (int r = 0; r < 4; ++r) { mrun[r] = -3e38f; lsum[r] = 0.f; }

  for (int jt = 0; jt < 16; ++jt) {
    const int j0 = jt * 64;
    const int jr_base = 1024 + j0 - i0 - 63;
    __syncthreads();
    // stage K tile and V^T tile
#pragma unroll
    for (int s = 0; s < 2; ++s) {
      int c = tid + 256 * s;
      int row = c >> 3, ko = (c & 7) * 8;
      *(uint4*)&sK[row][ko] = *(const uint4*)&kh[((j0 + row) * 2 + b) * 1024 + n * 64 + ko];
      *(uint4*)&sVT[row][ko] = *(const uint4*)&vT[(bn * 64 + row) * 1024 + j0 + ko];
    }
    // stage Kr band (128 rows)
#pragma unroll
    for (int s = 0; s < 4; ++s) {
      int c = tid + 256 * s;
      int row = c >> 3, ko = (c & 7) * 8;
      int jr = jr_base + row;
      if (jr > 2047) jr = 2047;  // last band row unused
      *(uint4*)&sKR[row][ko] = *(const uint4*)&krh[(jr * 2 + b) * 1024 + n * 64 + ko];
    }
    __syncthreads();

    // ac = (q+rw) . k
    f32x4 acc_ac[4];
#pragma unroll
    for (int nf = 0; nf < 4; ++nf) {
      f32x4 a = {0.f, 0.f, 0.f, 0.f};
#pragma unroll
      for (int ks = 0; ks < 2; ++ks) {
        bf16x8 fk = *(const bf16x8*)&sK[nf * 16 + lc][ks * 32 + g * 8];
        a = mfma16(fqw[ks], fk, a);
      }
      acc_ac[nf] = a;
    }
    // bd band = (q+rr) . kr  -> LDS (own-wave rows only)
#pragma unroll
    for (int nf = 0; nf < 8; ++nf) {
      f32x4 a = {0.f, 0.f, 0.f, 0.f};
#pragma unroll
      for (int ks = 0; ks < 2; ++ks) {
        bf16x8 fk = *(const bf16x8*)&sKR[nf * 16 + lc][ks * 32 + g * 8];
        a = mfma16(fqr[ks], fk, a);
      }
#pragma unroll
      for (int r = 0; r < 4; ++r)
        sBD[w * 16 + g * 4 + r][nf * 16 + lc] = f2bf(a[r]);
    }
    // assemble scores
    float p[4][4];
#pragma unroll
    for (int nf = 0; nf < 4; ++nf) {
#pragma unroll
      for (int r = 0; r < 4; ++r) {
        int iloc = w * 16 + g * 4 + r;
        int i = i0 + iloc;
        int jloc = nf * 16 + lc;
        int j = j0 + jloc;
        float sc = acc_ac[nf][r] + bf2f(sBD[iloc][jloc - iloc + 63]);
        int eidx = (i * 1024 + j) * 2 + b;
        sc += seg[eidx] ? ef1v[r] : ef0v[r];
        sc = sc * 0.125f - 1e30f * mask[eidx];
        p[r][nf] = sc;
      }
    }
    // online softmax per row
#pragma unroll
    for (int r = 0; r < 4; ++r) {
      float mt = fmaxf(fmaxf(p[r][0], p[r][1]), fmaxf(p[r][2], p[r][3]));
      mt = fmaxf(mt, __shfl_xor(mt, 1));
      mt = fmaxf(mt, __shfl_xor(mt, 2));
      mt = fmaxf(mt, __shfl_xor(mt, 4));
      mt = fmaxf(mt, __shfl_xor(mt, 8));
      float mnew = fmaxf(mrun[r], mt);
      float corr = __expf(mrun[r] - mnew);
      mrun[r] = mnew;
      float se = 0.f;
#pragma unroll
      for (int nf = 0; nf < 4; ++nf) {
        float e = __expf(p[r][nf] - mnew);
        p[r][nf] = e;
        se += e;
      }
      se += __shfl_xor(se, 1);
      se += __shfl_xor(se, 2);
      se += __shfl_xor(se, 4);
      se += __shfl_xor(se, 8);
      lsum[r] = lsum[r] * corr + se;
#pragma unroll
      for (int df = 0; df < 4; ++df) accO[df][r] *= corr;
#pragma unroll
      for (int nf = 0; nf < 4; ++nf)
        sP[w][g * 4 + r][nf * 16 + lc] = f2bf(p[r][nf]);
    }
    // pv accumulate
#pragma unroll
    for (int ks = 0; ks < 2; ++ks) {
      bf16x8 fp = *(const bf16x8*)&sP[w][lc][ks * 32 + g * 8];
#pragma unroll
      for (int df = 0; df < 4; ++df) {
        bf16x8 fv = *(const bf16x8*)&sVT[df * 16 + lc][ks * 32 + g * 8];
        accO[df] = mfma16(fp, fv, accO[df]);
      }
    }
  }
  // write attn_vec (bf16)
#pragma unroll
  for (int r = 0; r < 4; ++r) {
    float inv = 1.f / lsum[r];
    int i = i0 + w * 16 + g * 4 + r;
#pragma unroll
    for (int df = 0; df < 4; ++df)
      av[(i * 2 + b) * 1024 + n * 64 + df * 16 + lc] = f2bf(accO[df][r] * inv);
  }
}

// ---------------- residual + LayerNorm ----------------
__global__ __launch_bounds__(256) void ln_kernel(const float* __restrict__ gout,
                                                 const float* __restrict__ h,
                                                 const float* __restrict__ gamma,
                                                 const float* __restrict__ beta,
                                                 float* __restrict__ out) {
  __shared__ float red[8];
  const int row = blockIdx.x;
  const int tid = threadIdx.x;
  float x[4];
  float s = 0.f;
#pragma unroll
  for (int q = 0; q < 4; ++q) {
    int d = tid + q * 256;
    x[q] = gout[row * 1024 + d] + h[row * 1024 + d];
    s += x[q];
  }
#pragma unroll
  for (int m = 1; m < 64; m <<= 1) s += __shfl_xor(s, m);
  if ((tid & 63) == 0) red[tid >> 6] = s;
  __syncthreads();
  s = red[0] + red[1] + red[2] + red[3];
  float mu = s * (1.f / 1024.f);
  float v = 0.f;
#pragma unroll
  for (int q = 0; q < 4; ++q) {
    float dd = x[q] - mu;
    v += dd * dd;
  }
#pragma unroll
  for (int m = 1; m < 64; m <<= 1) v += __shfl_xor(v, m);
  if ((tid & 63) == 0) red[4 + (tid >> 6)] = v;
  __syncthreads();
  v = red[4] + red[5] + red[6] + red[7];
  float rstd = rsqrtf(v * (1.f / 1024.f) + 1e-12f);
#pragma unroll
  for (int q = 0; q < 4; ++q) {
    int d = tid + q * 256;
    out[row * 1024 + d] = (x[q] - mu) * rstd * gamma[d] + beta[d];
  }
}

extern "C" void kernel_launch(void* const* d_in, const int* in_sizes, int n_in,
                              void* d_out, int out_size, void* d_ws, size_t ws_size,
                              hipStream_t stream) {
  const float* h = (const float*)d_in[0];
  const float* r = (const float*)d_in[1];
  const unsigned char* seg = (const unsigned char*)d_in[2];
  const float* mask = (const float*)d_in[3];
  const float* wq = (const float*)d_in[4];
  const float* wk = (const float*)d_in[5];
  const float* wv = (const float*)d_in[6];
  const float* wr = (const float*)d_in[7];
  const float* wo = (const float*)d_in[8];
  const float* rwb = (const float*)d_in[9];
  const float* rrb = (const float*)d_in[10];
  const float* rsb = (const float*)d_in[11];
  const float* seg_embed = (const float*)d_in[12];
  const float* gamma = (const float*)d_in[13];
  const float* beta = (const float*)d_in[14];
  float* out = (float*)d_out;

  char* ws = (char*)d_ws;
  size_t off = 0;
  auto alloc = [&](size_t bytes) {
    size_t cur = off;
    off = (off + bytes + 255) & ~(size_t)255;
    return cur;
  };
  unsigned short* hb = (unsigned short*)(ws + alloc(2048 * 1024 * 2));
  unsigned short* rb = (unsigned short*)(ws + alloc(4096 * 1024 * 2));
  unsigned short* wq_t = (unsigned short*)(ws + alloc(1024 * 1024 * 2));
  unsigned short* wk_t = (unsigned short*)(ws + alloc(1024 * 1024 * 2));
  unsigned short* wv_t = (unsigned short*)(ws + alloc(1024 * 1024 * 2));
  unsigned short* wr_t = (unsigned short*)(ws + alloc(1024 * 1024 * 2));
  unsigned short* wo_b = (unsigned short*)(ws + alloc(1024 * 1024 * 2));
  unsigned short* qwb = (unsigned short*)(ws + alloc(2048 * 1024 * 2));
  unsigned short* qrb = (unsigned short*)(ws + alloc(2048 * 1024 * 2));
  unsigned short* qsb = (unsigned short*)(ws + alloc(2048 * 1024 * 2));
  unsigned short* khb = (unsigned short*)(ws + alloc(2048 * 1024 * 2));
  unsigned short* vhb = (unsigned short*)(ws + alloc(2048 * 1024 * 2));
  unsigned short* krhb = (unsigned short*)(ws + alloc(4096 * 1024 * 2));
  unsigned short* vTb = (unsigned short*)(ws + alloc(2048 * 1024 * 2));
  float* ef0 = (float*)(ws + alloc(2048 * 16 * 4));
  float* ef1 = (float*)(ws + alloc(2048 * 16 * 4));
  unsigned short* avb = (unsigned short*)(ws + alloc(2048 * 1024 * 2));
  float* gout = (float*)(ws + alloc(2048 * 1024 * 4));
  (void)ws_size; (void)in_sizes; (void)n_in; (void)out_size;

  // casts
  cast_kernel<<<2048, 256, 0, stream>>>(h, hb, 2048 * 1024 / 4);
  cast_kernel<<<4096, 256, 0, stream>>>(r, rb, 4096 * 1024 / 4);
  cast_kernel<<<1024, 256, 0, stream>>>(wo, wo_b, 1024 * 1024 / 4);
  dim3 tg(32, 32);
  transpose_cast<<<tg, 256, 0, stream>>>(wq, wq_t);
  transpose_cast<<<tg, 256, 0, stream>>>(wk, wk_t);
  transpose_cast<<<tg, 256, 0, stream>>>(wv, wv_t);
  transpose_cast<<<tg, 256, 0, stream>>>(wr, wr_t);

  // projections
  dim3 gq(8, 16);
  gemm_bt<3, false><<<gq, 256, 0, stream>>>(hb, wq_t, 2048, 1024, 1024,
                                            qwb, rwb, qrb, rrb, qsb, rsb);
  gemm_bt<1, false><<<gq, 256, 0, stream>>>(hb, wk_t, 2048, 1024, 1024,
                                            khb, nullptr, nullptr, nullptr, nullptr, nullptr);
  gemm_bt<1, false><<<gq, 256, 0, stream>>>(hb, wv_t, 2048, 1024, 1024,
                                            vhb, nullptr, nullptr, nullptr, nullptr, nullptr);
  dim3 gr(8, 32);
  gemm_bt<1, false><<<gr, 256, 0, stream>>>(rb, wr_t, 4096, 1024, 1024,
                                            krhb, nullptr, nullptr, nullptr, nullptr, nullptr);

  transpose_v<<<dim3(16, 32), 256, 0, stream>>>(vhb, vTb);
  ef_kernel<<<8192, 256, 0, stream>>>(qsb, seg_embed, ef0, ef1);

  attn_kernel<<<dim3(16, 32), 256, 0, stream>>>(qwb, qrb, khb, krhb, vTb,
                                                ef0, ef1, seg, mask, avb);

  gemm_bt<1, true><<<gq, 256, 0, stream>>>(avb, wo_b, 2048, 1024, 1024,
                                           gout, nullptr, nullptr, nullptr, nullptr, nullptr);
  ln_kernel<<<2048, 256, 0, stream>>>(gout, h, gamma, beta, out);
}

// Round 2
// 223.527 us; speedup vs baseline: 1.5297x; 1.5297x over previous
//
#include <hip/hip_runtime.h>

typedef __bf16 bf16x8 __attribute__((ext_vector_type(8)));
typedef float f32x4 __attribute__((ext_vector_type(4)));
typedef unsigned short us4 __attribute__((ext_vector_type(4)));

__device__ __forceinline__ unsigned short f2bf(float f) {
  unsigned int u = __builtin_bit_cast(unsigned int, f);
  u += 0x7fffu + ((u >> 16) & 1u);
  return (unsigned short)(u >> 16);
}
__device__ __forceinline__ float bf2f(unsigned short s) {
  unsigned int u = ((unsigned int)s) << 16;
  return __builtin_bit_cast(float, u);
}
__device__ __forceinline__ f32x4 mfma16(bf16x8 a, bf16x8 b, f32x4 c) {
  return __builtin_amdgcn_mfma_f32_16x16x32_bf16(a, b, c, 0, 0, 0);
}
__device__ __forceinline__ void gload16(const void* g, void* l) {
  __builtin_amdgcn_global_load_lds(
      (const __attribute__((address_space(1))) unsigned int*)g,
      (__attribute__((address_space(3))) unsigned int*)l, 16, 0, 0);
}

// ---------------- cast f32 -> bf16 (vectorized) ----------------
__global__ __launch_bounds__(256) void cast_kernel(const float* __restrict__ in,
                                                   unsigned short* __restrict__ out, int n4) {
  int idx = blockIdx.x * 256 + threadIdx.x;
  if (idx < n4) {
    float4 v = ((const float4*)in)[idx];
    us4 o;
    o[0] = f2bf(v.x); o[1] = f2bf(v.y); o[2] = f2bf(v.z); o[3] = f2bf(v.w);
    *(us4*)&out[idx * 4] = o;
  }
}

// ---------------- transpose+cast 4 weights [1024][1024] f32 -> [N][K] bf16 ----------------
__global__ __launch_bounds__(256) void transpose_cast4(
    const float* __restrict__ w0, const float* __restrict__ w1,
    const float* __restrict__ w2, const float* __restrict__ w3,
    unsigned short* __restrict__ o0, unsigned short* __restrict__ o1,
    unsigned short* __restrict__ o2, unsigned short* __restrict__ o3) {
  __shared__ float t[32][33];
  const int z = blockIdx.z;
  const float* in = z == 0 ? w0 : (z == 1 ? w1 : (z == 2 ? w2 : w3));
  unsigned short* out = z == 0 ? o0 : (z == 1 ? o1 : (z == 2 ? o2 : o3));
  int k0 = blockIdx.y * 32;
  int n0 = blockIdx.x * 32;
  int r = threadIdx.x >> 5;
  int c = threadIdx.x & 31;
#pragma unroll
  for (int s = 0; s < 4; ++s)
    t[r + s * 8][c] = in[(k0 + r + s * 8) * 1024 + n0 + c];
  __syncthreads();
#pragma unroll
  for (int s = 0; s < 4; ++s)
    out[(n0 + r + s * 8) * 1024 + k0 + c] = f2bf(t[c][r + s * 8]);
}

// ---------------- segmask: pack {bf16(-1e30*mask), bf16(seg)} per (b,i,j) ----------------
__global__ __launch_bounds__(256) void segmask_kernel(const unsigned char* __restrict__ seg,
                                                      const float* __restrict__ mask,
                                                      unsigned int* __restrict__ out) {
  int ij = blockIdx.x * 256 + threadIdx.x;  // 0 .. 2^20-1
  unsigned short sv = *(const unsigned short*)&seg[ij * 2];
  float2 mv = *(const float2*)&mask[(size_t)ij * 2];
  unsigned int o0 = ((unsigned int)f2bf(mv.x * -1e30f) << 16) | ((sv & 0xffu) ? 0x3f80u : 0u);
  unsigned int o1 = ((unsigned int)f2bf(mv.y * -1e30f) << 16) | ((sv >> 8) ? 0x3f80u : 0u);
  out[ij] = o0;
  out[1048576 + ij] = o1;
}

// ---------------- m97-style GEMM core: 128x128 tile, K=1024, global_load_lds ----------------
__device__ __forceinline__ void gemm_core128(const unsigned short* __restrict__ A,
                                             const unsigned short* __restrict__ Bt,
                                             int m0, int n0,
                                             unsigned short* sA, unsigned short* sB,
                                             int tid, f32x4 (&acc)[4][4]) {
  const int lane = tid & 63, w = tid >> 6;
  const int wm = w >> 1, wn = w & 1, g = lane >> 4, lc = lane & 15;
  for (int kt = 0; kt < 1024; kt += 32) {
    __syncthreads();
#pragma unroll
    for (int s = 0; s < 2; ++s) {
      int c = s * 256 + tid;
      int row = c >> 2, ko = (c & 3) * 8;
      int lbase = (s * 256 + w * 64) * 8;
      gload16(&A[(size_t)(m0 + row) * 1024 + kt + ko], &sA[lbase]);
      gload16(&Bt[(size_t)(n0 + row) * 1024 + kt + ko], &sB[lbase]);
    }
    __syncthreads();
    bf16x8 af[4], bfr[4];
#pragma unroll
    for (int i = 0; i < 4; ++i) {
      af[i] = *(const bf16x8*)&sA[(wm * 64 + i * 16 + lc) * 32 + g * 8];
      bfr[i] = *(const bf16x8*)&sB[(wn * 64 + i * 16 + lc) * 32 + g * 8];
    }
#pragma unroll
    for (int mi = 0; mi < 4; ++mi)
#pragma unroll
      for (int ni = 0; ni < 4; ++ni)
        acc[mi][ni] = mfma16(af[mi], bfr[ni], acc[mi][ni]);
  }
}

// ---------------- generic GEMM (r-proj, out-proj) ----------------
template <bool F32OUT>
__global__ __launch_bounds__(256) void gemm97(const unsigned short* __restrict__ A,
                                              const unsigned short* __restrict__ Bt,
                                              void* __restrict__ C0) {
  __shared__ unsigned short sA[128 * 32];
  __shared__ unsigned short sB[128 * 32];
  const int tid = threadIdx.x, lane = tid & 63, w = tid >> 6;
  const int wm = w >> 1, wn = w & 1, g = lane >> 4, lc = lane & 15;
  const int m0 = blockIdx.y * 128, n0 = blockIdx.x * 128;
  f32x4 acc[4][4] = {};
  gemm_core128(A, Bt, m0, n0, sA, sB, tid, acc);
#pragma unroll
  for (int ni = 0; ni < 4; ++ni) {
    int col = n0 + wn * 64 + ni * 16 + lc;
#pragma unroll
    for (int mi = 0; mi < 4; ++mi) {
      int rowb = m0 + wm * 64 + mi * 16 + g * 4;
#pragma unroll
      for (int r = 0; r < 4; ++r) {
        float v = acc[mi][ni][r];
        size_t idx = (size_t)(rowb + r) * 1024 + col;
        if (F32OUT) ((float*)C0)[idx] = v;
        else ((unsigned short*)C0)[idx] = f2bf(v);
      }
    }
  }
}

// ---------------- fused q/k/v projection (sel by blockIdx.x>>3), q outputs pre-scaled ----------------
__global__ __launch_bounds__(256) void proj_kernel(
    const unsigned short* __restrict__ hb,
    const unsigned short* __restrict__ wq_t, const unsigned short* __restrict__ wk_t,
    const unsigned short* __restrict__ wv_t,
    const float* __restrict__ rwb, const float* __restrict__ rrb, const float* __restrict__ rsb,
    unsigned short* __restrict__ qwb, unsigned short* __restrict__ qrb,
    unsigned short* __restrict__ qsb,
    unsigned short* __restrict__ khb, unsigned short* __restrict__ vhb) {
  __shared__ unsigned short sA[128 * 32];
  __shared__ unsigned short sB[128 * 32];
  const int sel = blockIdx.x >> 3;
  const int n0 = (blockIdx.x & 7) * 128;
  const int m0 = blockIdx.y * 128;
  const unsigned short* Bt = sel == 0 ? wq_t : (sel == 1 ? wk_t : wv_t);
  const int tid = threadIdx.x, lane = tid & 63, w = tid >> 6;
  const int wm = w >> 1, wn = w & 1, g = lane >> 4, lc = lane & 15;
  f32x4 acc[4][4] = {};
  gemm_core128(hb, Bt, m0, n0, sA, sB, tid, acc);
#pragma unroll
  for (int ni = 0; ni < 4; ++ni) {
    int col = n0 + wn * 64 + ni * 16 + lc;
    float bw = 0.f, br = 0.f, bs = 0.f;
    if (sel == 0) { bw = rwb[col]; br = rrb[col]; bs = rsb[col]; }
#pragma unroll
    for (int mi = 0; mi < 4; ++mi) {
      int rowb = m0 + wm * 64 + mi * 16 + g * 4;
#pragma unroll
      for (int r = 0; r < 4; ++r) {
        float v = acc[mi][ni][r];
        size_t idx = (size_t)(rowb + r) * 1024 + col;
        if (sel == 0) {
          qwb[idx] = f2bf((v + bw) * 0.125f);
          qrb[idx] = f2bf((v + br) * 0.125f);
          qsb[idx] = f2bf((v + bs) * 0.125f);
        } else if (sel == 1) {
          khb[idx] = f2bf(v);
        } else {
          vhb[idx] = f2bf(v);
        }
      }
    }
  }
}

// ---------------- V transpose: vh[(j*B+b)*1024 + n*64+d] -> vT[(bn*64+d)*1024 + j] ----------------
__global__ __launch_bounds__(256) void transpose_v(const unsigned short* __restrict__ vh,
                                                   unsigned short* __restrict__ vT) {
  __shared__ unsigned short t[64][65];
  const int bn = blockIdx.y, j0 = blockIdx.x * 64;
  const int b = bn >> 4, n = bn & 15;
  const int r = threadIdx.x >> 4;
  const int c4 = (threadIdx.x & 15) * 4;
#pragma unroll
  for (int s = 0; s < 4; ++s) {
    int j = r + s * 16;
    us4 v = *(const us4*)&vh[((size_t)(j0 + j) * 2 + b) * 1024 + n * 64 + c4];
    t[j][c4 + 0] = v[0]; t[j][c4 + 1] = v[1]; t[j][c4 + 2] = v[2]; t[j][c4 + 3] = v[3];
  }
  __syncthreads();
#pragma unroll
  for (int s = 0; s < 4; ++s) {
    int d = r + s * 16;
    us4 v;
    v[0] = t[c4 + 0][d]; v[1] = t[c4 + 1][d]; v[2] = t[c4 + 2][d]; v[3] = t[c4 + 3][d];
    *(us4*)&vT[((size_t)bn * 64 + d) * 1024 + j0 + c4] = v;
  }
}

// ---------------- ef0/ef1 per (i,b,n): dot of (pre-scaled) qs row with seg_embed ----------------
__global__ __launch_bounds__(256) void ef_kernel(const unsigned short* __restrict__ qs,
                                                 const float* __restrict__ seg_embed,
                                                 float* __restrict__ ef0, float* __restrict__ ef1) {
  int gw = blockIdx.x * 4 + (threadIdx.x >> 6);
  int lane = threadIdx.x & 63;
  int n = gw & 15, ib = gw >> 4;  // ib = i*2+b
  int i = ib >> 1, b = ib & 1;
  float qv = bf2f(qs[(size_t)ib * 1024 + n * 64 + lane]);
  float p0 = qv * seg_embed[n * 64 + lane];
  float p1 = qv * seg_embed[1024 + n * 64 + lane];
#pragma unroll
  for (int m = 1; m < 64; m <<= 1) {
    p0 += __shfl_xor(p0, m);
    p1 += __shfl_xor(p1, m);
  }
  if (lane == 0) {
    ef0[(b * 16 + n) * 1024 + i] = p0;
    ef1[(b * 16 + n) * 1024 + i] = p1;
  }
}

// ---------------- fused relative attention (flash-style, in-register bd gather) ----------------
__global__ __launch_bounds__(256) void attn_kernel(
    const unsigned short* __restrict__ qw, const unsigned short* __restrict__ qr,
    const unsigned short* __restrict__ kh, const unsigned short* __restrict__ krh,
    const unsigned short* __restrict__ vT,
    const float* __restrict__ ef0, const float* __restrict__ ef1,
    const unsigned int* __restrict__ segmask,
    unsigned short* __restrict__ av) {
  __shared__ unsigned short sK[64][72];    // K tile  [j][d]
  __shared__ unsigned short sKR[128][72];  // Kr band [jr][d]
  __shared__ unsigned short sVT[64][72];   // V^T     [d][j]
  __shared__ unsigned short sP[4][16][72]; // per-wave P tile [i][j]

  const int tid = threadIdx.x, lane = tid & 63, w = tid >> 6;
  const int g = lane >> 4, lc = lane & 15;
  const int bn = blockIdx.y, b = bn >> 4, n = bn & 15;
  const int i0 = blockIdx.x * 64;

  bf16x8 fqw[2], fqr[2];
  const int qrow = i0 + w * 16 + lc;
#pragma unroll
  for (int ks = 0; ks < 2; ++ks) {
    size_t off = ((size_t)qrow * 2 + b) * 1024 + n * 64 + ks * 32 + g * 8;
    fqw[ks] = *(const bf16x8*)&qw[off];
    fqr[ks] = *(const bf16x8*)&qr[off];
  }
  float ef0v[4], dv[4];
#pragma unroll
  for (int r = 0; r < 4; ++r) {
    int i = i0 + w * 16 + g * 4 + r;
    float e0 = ef0[bn * 1024 + i];
    ef0v[r] = e0;
    dv[r] = ef1[bn * 1024 + i] - e0;
  }
  float mrun[4], lsum[4];
  f32x4 accO[4] = {};
#pragma unroll
  for (int r = 0; r < 4; ++r) { mrun[r] = -3e38f; lsum[r] = 0.f; }

  for (int jt = 0; jt < 16; ++jt) {
    const int j0 = jt * 64;
    const int jr_base = 1024 + j0 - i0 - 63;
    __syncthreads();
#pragma unroll
    for (int s = 0; s < 2; ++s) {
      int c = tid + 256 * s;
      int row = c >> 3, ko = (c & 7) * 8;
      *(uint4*)&sK[row][ko] = *(const uint4*)&kh[((size_t)(j0 + row) * 2 + b) * 1024 + n * 64 + ko];
      *(uint4*)&sVT[row][ko] = *(const uint4*)&vT[((size_t)bn * 64 + row) * 1024 + j0 + ko];
    }
#pragma unroll
    for (int s = 0; s < 4; ++s) {
      int c = tid + 256 * s;
      int row = c >> 3, ko = (c & 7) * 8;
      int jr = jr_base + row;
      if (jr > 2047) jr = 2047;
      *(uint4*)&sKR[row][ko] = *(const uint4*)&krh[((size_t)jr * 2 + b) * 1024 + n * 64 + ko];
    }
    __syncthreads();

    // ac = (q+rw)·k  (pre-scaled)
    f32x4 acc_ac[4];
#pragma unroll
    for (int nf = 0; nf < 4; ++nf) {
      f32x4 a = {0.f, 0.f, 0.f, 0.f};
#pragma unroll
      for (int ks = 0; ks < 2; ++ks) {
        bf16x8 fk = *(const bf16x8*)&sK[nf * 16 + lc][ks * 32 + g * 8];
        a = mfma16(fqw[ks], fk, a);
      }
      acc_ac[nf] = a;
    }
    // bd sub-band for this wave: fragments cover jr_loc in [(3-w)*16, (3-w)*16+79]
    f32x4 bdk[5];
#pragma unroll
    for (int k = 0; k < 5; ++k) {
      f32x4 a = {0.f, 0.f, 0.f, 0.f};
#pragma unroll
      for (int ks = 0; ks < 2; ++ks) {
        bf16x8 fk = *(const bf16x8*)&sKR[(3 - w + k) * 16 + lc][ks * 32 + g * 8];
        a = mfma16(fqr[ks], fk, a);
      }
      bdk[k] = a;
    }
    // assemble scores: bd[i][j] = bdk-band element via in-group rotation
    float p[4][4];
#pragma unroll
    for (int r = 0; r < 4; ++r) {
      const int a_idx = g * 4 + r;
      const int srcl = (lane & 48) | ((lc + 15 - a_idx) & 15);
      const bool lo = lc <= a_idx;
      const int i = i0 + w * 16 + a_idx;
#pragma unroll
      for (int nf = 0; nf < 4; ++nf) {
        float vlo = __shfl(bdk[nf][r], srcl);
        float vhi = __shfl(bdk[nf + 1][r], srcl);
        float bdv = lo ? vlo : vhi;
        int j = j0 + nf * 16 + lc;
        unsigned int ms = segmask[((unsigned)b << 20) | ((unsigned)i << 10) | (unsigned)j];
        float sc = acc_ac[nf][r] + bdv + ef0v[r] + bf2f((unsigned short)(ms & 0xffffu)) * dv[r] +
                   bf2f((unsigned short)(ms >> 16));
        p[r][nf] = sc;
      }
    }
    // online softmax per row (reduce over 16 lanes in group)
#pragma unroll
    for (int r = 0; r < 4; ++r) {
      float mt = fmaxf(fmaxf(p[r][0], p[r][1]), fmaxf(p[r][2], p[r][3]));
      mt = fmaxf(mt, __shfl_xor(mt, 1));
      mt = fmaxf(mt, __shfl_xor(mt, 2));
      mt = fmaxf(mt, __shfl_xor(mt, 4));
      mt = fmaxf(mt, __shfl_xor(mt, 8));
      float mnew = fmaxf(mrun[r], mt);
      float corr = __expf(mrun[r] - mnew);
      mrun[r] = mnew;
      float se = 0.f;
#pragma unroll
      for (int nf = 0; nf < 4; ++nf) {
        float e = __expf(p[r][nf] - mnew);
        p[r][nf] = e;
        se += e;
      }
      se += __shfl_xor(se, 1);
      se += __shfl_xor(se, 2);
      se += __shfl_xor(se, 4);
      se += __shfl_xor(se, 8);
      lsum[r] = lsum[r] * corr + se;
#pragma unroll
      for (int df = 0; df < 4; ++df) accO[df][r] *= corr;
#pragma unroll
      for (int nf = 0; nf < 4; ++nf)
        sP[w][g * 4 + r][nf * 16 + lc] = f2bf(p[r][nf]);
    }
    // pv accumulate
#pragma unroll
    for (int ks = 0; ks < 2; ++ks) {
      bf16x8 fp = *(const bf16x8*)&sP[w][lc][ks * 32 + g * 8];
#pragma unroll
      for (int df = 0; df < 4; ++df) {
        bf16x8 fv = *(const bf16x8*)&sVT[df * 16 + lc][ks * 32 + g * 8];
        accO[df] = mfma16(fp, fv, accO[df]);
      }
    }
  }
#pragma unroll
  for (int r = 0; r < 4; ++r) {
    float inv = 1.f / lsum[r];
    int i = i0 + w * 16 + g * 4 + r;
#pragma unroll
    for (int df = 0; df < 4; ++df)
      av[((size_t)i * 2 + b) * 1024 + n * 64 + df * 16 + lc] = f2bf(accO[df][r] * inv);
  }
}

// ---------------- residual + LayerNorm ----------------
__global__ __launch_bounds__(256) void ln_kernel(const float* __restrict__ gout,
                                                 const float* __restrict__ h,
                                                 const float* __restrict__ gamma,
                                                 const float* __restrict__ beta,
                                                 float* __restrict__ out) {
  __shared__ float red[8];
  const int row = blockIdx.x;
  const int tid = threadIdx.x;
  float x[4];
  float s = 0.f;
#pragma unroll
  for (int q = 0; q < 4; ++q) {
    int d = tid + q * 256;
    x[q] = gout[(size_t)row * 1024 + d] + h[(size_t)row * 1024 + d];
    s += x[q];
  }
#pragma unroll
  for (int m = 1; m < 64; m <<= 1) s += __shfl_xor(s, m);
  if ((tid & 63) == 0) red[tid >> 6] = s;
  __syncthreads();
  s = red[0] + red[1] + red[2] + red[3];
  float mu = s * (1.f / 1024.f);
  float v = 0.f;
#pragma unroll
  for (int q = 0; q < 4; ++q) {
    float dd = x[q] - mu;
    v += dd * dd;
  }
#pragma unroll
  for (int m = 1; m < 64; m <<= 1) v += __shfl_xor(v, m);
  if ((tid & 63) == 0) red[4 + (tid >> 6)] = v;
  __syncthreads();
  v = red[4] + red[5] + red[6] + red[7];
  float rstd = rsqrtf(v * (1.f / 1024.f) + 1e-12f);
#pragma unroll
  for (int q = 0; q < 4; ++q) {
    int d = tid + q * 256;
    out[(size_t)row * 1024 + d] = (x[q] - mu) * rstd * gamma[d] + beta[d];
  }
}

extern "C" void kernel_launch(void* const* d_in, const int* in_sizes, int n_in,
                              void* d_out, int out_size, void* d_ws, size_t ws_size,
                              hipStream_t stream) {
  const float* h = (const float*)d_in[0];
  const float* r = (const float*)d_in[1];
  const unsigned char* seg = (const unsigned char*)d_in[2];
  const float* mask = (const float*)d_in[3];
  const float* wq = (const float*)d_in[4];
  const float* wk = (const float*)d_in[5];
  const float* wv = (const float*)d_in[6];
  const float* wr = (const float*)d_in[7];
  const float* wo = (const float*)d_in[8];
  const float* rwb = (const float*)d_in[9];
  const float* rrb = (const float*)d_in[10];
  const float* rsb = (const float*)d_in[11];
  const float* seg_embed = (const float*)d_in[12];
  const float* gamma = (const float*)d_in[13];
  const float* beta = (const float*)d_in[14];
  float* out = (float*)d_out;

  char* ws = (char*)d_ws;
  size_t off = 0;
  auto alloc = [&](size_t bytes) {
    size_t cur = off;
    off = (off + bytes + 255) & ~(size_t)255;
    return cur;
  };
  unsigned short* hb = (unsigned short*)(ws + alloc(2048 * 1024 * 2));
  unsigned short* rb = (unsigned short*)(ws + alloc(4096 * 1024 * 2));
  unsigned short* wq_t = (unsigned short*)(ws + alloc(1024 * 1024 * 2));
  unsigned short* wk_t = (unsigned short*)(ws + alloc(1024 * 1024 * 2));
  unsigned short* wv_t = (unsigned short*)(ws + alloc(1024 * 1024 * 2));
  unsigned short* wr_t = (unsigned short*)(ws + alloc(1024 * 1024 * 2));
  unsigned short* wo_b = (unsigned short*)(ws + alloc(1024 * 1024 * 2));
  unsigned short* qwb = (unsigned short*)(ws + alloc(2048 * 1024 * 2));
  unsigned short* qrb = (unsigned short*)(ws + alloc(2048 * 1024 * 2));
  unsigned short* qsb = (unsigned short*)(ws + alloc(2048 * 1024 * 2));
  unsigned short* khb = (unsigned short*)(ws + alloc(2048 * 1024 * 2));
  unsigned short* vhb = (unsigned short*)(ws + alloc(2048 * 1024 * 2));
  unsigned short* krhb = (unsigned short*)(ws + alloc(4096 * 1024 * 2));
  unsigned short* vTb = (unsigned short*)(ws + alloc(2048 * 1024 * 2));
  float* ef0 = (float*)(ws + alloc(2048 * 16 * 4));
  float* ef1 = (float*)(ws + alloc(2048 * 16 * 4));
  unsigned int* segmask = (unsigned int*)(ws + alloc(2 * 1024 * 1024 * 4));
  unsigned short* avb = (unsigned short*)(ws + alloc(2048 * 1024 * 2));
  float* gout = (float*)(ws + alloc(2048 * 1024 * 4));
  (void)ws_size; (void)in_sizes; (void)n_in; (void)out_size;

  cast_kernel<<<2048, 256, 0, stream>>>(h, hb, 2048 * 1024 / 4);
  cast_kernel<<<4096, 256, 0, stream>>>(r, rb, 4096 * 1024 / 4);
  cast_kernel<<<1024, 256, 0, stream>>>(wo, wo_b, 1024 * 1024 / 4);
  transpose_cast4<<<dim3(32, 32, 4), 256, 0, stream>>>(wq, wk, wv, wr, wq_t, wk_t, wv_t, wr_t);
  segmask_kernel<<<4096, 256, 0, stream>>>(seg, mask, segmask);

  proj_kernel<<<dim3(24, 16), 256, 0, stream>>>(hb, wq_t, wk_t, wv_t, rwb, rrb, rsb,
                                                qwb, qrb, qsb, khb, vhb);
  gemm97<false><<<dim3(8, 32), 256, 0, stream>>>(rb, wr_t, krhb);

  transpose_v<<<dim3(16, 32), 256, 0, stream>>>(vhb, vTb);
  ef_kernel<<<8192, 256, 0, stream>>>(qsb, seg_embed, ef0, ef1);

  attn_kernel<<<dim3(16, 32), 256, 0, stream>>>(qwb, qrb, khb, krhb, vTb,
                                                ef0, ef1, segmask, avb);

  gemm97<true><<<dim3(8, 16), 256, 0, stream>>>(avb, wo_b, gout);
  ln_kernel<<<2048, 256, 0, stream>>>(gout, h, gamma, beta, out);
}

// Round 3
// 155.744 us; speedup vs baseline: 2.1955x; 1.4352x over previous
//
#include <hip/hip_runtime.h>

typedef __bf16 bf16x8 __attribute__((ext_vector_type(8)));
typedef float f32x4 __attribute__((ext_vector_type(4)));
typedef unsigned short us4 __attribute__((ext_vector_type(4)));

__device__ __forceinline__ unsigned short f2bf(float f) {
  unsigned int u = __builtin_bit_cast(unsigned int, f);
  u += 0x7fffu + ((u >> 16) & 1u);
  return (unsigned short)(u >> 16);
}
__device__ __forceinline__ float bf2f(unsigned short s) {
  unsigned int u = ((unsigned int)s) << 16;
  return __builtin_bit_cast(float, u);
}
__device__ __forceinline__ f32x4 mfma16(bf16x8 a, bf16x8 b, f32x4 c) {
  return __builtin_amdgcn_mfma_f32_16x16x32_bf16(a, b, c, 0, 0, 0);
}
__device__ __forceinline__ void gload16(const void* g, void* l) {
  __builtin_amdgcn_global_load_lds(
      (const __attribute__((address_space(1))) unsigned int*)g,
      (__attribute__((address_space(3))) unsigned int*)l, 16, 0, 0);
}
template <int CTRL>
__device__ __forceinline__ float dppf(float x) {
  return __builtin_bit_cast(
      float, __builtin_amdgcn_mov_dpp(__builtin_bit_cast(int, x), CTRL, 0xf, 0xf, true));
}
// full 16-lane-row reduce via DPP (VALU pipe, no LDS)
__device__ __forceinline__ float rmax16(float x) {
  x = fmaxf(x, dppf<0xB1>(x));   // quad_perm xor1
  x = fmaxf(x, dppf<0x4E>(x));   // quad_perm xor2
  x = fmaxf(x, dppf<0x124>(x));  // row_ror:4
  x = fmaxf(x, dppf<0x128>(x));  // row_ror:8
  return x;
}
__device__ __forceinline__ float rsum16(float x) {
  x += dppf<0xB1>(x);
  x += dppf<0x4E>(x);
  x += dppf<0x124>(x);
  x += dppf<0x128>(x);
  return x;
}

// ---------------- fused cast f32 -> bf16 for h, r, wo ----------------
__global__ __launch_bounds__(256) void cast3_kernel(
    const float* __restrict__ h, const float* __restrict__ r, const float* __restrict__ wo,
    unsigned short* __restrict__ hb, unsigned short* __restrict__ rb,
    unsigned short* __restrict__ wo_b) {
  int idx = blockIdx.x * 256 + threadIdx.x;  // float4 index
  const float* in;
  unsigned short* out;
  int o;
  if (idx < 524288) { in = h; out = hb; o = idx; }
  else if (idx < 1572864) { in = r; out = rb; o = idx - 524288; }
  else { in = wo; out = wo_b; o = idx - 1572864; }
  float4 v = ((const float4*)in)[o];
  us4 t;
  t[0] = f2bf(v.x); t[1] = f2bf(v.y); t[2] = f2bf(v.z); t[3] = f2bf(v.w);
  *(us4*)&out[o * 4] = t;
}

// ---------------- transpose+cast 4 weights [1024][1024] f32 -> [N][K] bf16 ----------------
__global__ __launch_bounds__(256) void transpose_cast4(
    const float* __restrict__ w0, const float* __restrict__ w1,
    const float* __restrict__ w2, const float* __restrict__ w3,
    unsigned short* __restrict__ o0, unsigned short* __restrict__ o1,
    unsigned short* __restrict__ o2, unsigned short* __restrict__ o3) {
  __shared__ float t[32][33];
  const int z = blockIdx.z;
  const float* in = z == 0 ? w0 : (z == 1 ? w1 : (z == 2 ? w2 : w3));
  unsigned short* out = z == 0 ? o0 : (z == 1 ? o1 : (z == 2 ? o2 : o3));
  int k0 = blockIdx.y * 32;
  int n0 = blockIdx.x * 32;
  int r = threadIdx.x >> 5;
  int c = threadIdx.x & 31;
#pragma unroll
  for (int s = 0; s < 4; ++s)
    t[r + s * 8][c] = in[(k0 + r + s * 8) * 1024 + n0 + c];
  __syncthreads();
#pragma unroll
  for (int s = 0; s < 4; ++s)
    out[(n0 + r + s * 8) * 1024 + k0 + c] = f2bf(t[c][r + s * 8]);
}

// ---------------- segmask: pack {bf16(-1e30*mask), bf16(seg)} per (b,i,j) ----------------
__global__ __launch_bounds__(256) void segmask_kernel(const unsigned char* __restrict__ seg,
                                                      const float* __restrict__ mask,
                                                      unsigned int* __restrict__ out) {
  int ij = blockIdx.x * 256 + threadIdx.x;
  unsigned short sv = *(const unsigned short*)&seg[ij * 2];
  float2 mv = *(const float2*)&mask[(size_t)ij * 2];
  unsigned int o0 = ((unsigned int)f2bf(mv.x * -1e30f) << 16) | ((sv & 0xffu) ? 0x3f80u : 0u);
  unsigned int o1 = ((unsigned int)f2bf(mv.y * -1e30f) << 16) | ((sv >> 8) ? 0x3f80u : 0u);
  out[ij] = o0;
  out[1048576 + ij] = o1;
}

// ---------------- m97-style GEMM core: 128x128 tile, K=1024, global_load_lds ----------------
__device__ __forceinline__ void gemm_core128(const unsigned short* __restrict__ A,
                                             const unsigned short* __restrict__ Bt,
                                             int m0, int n0,
                                             unsigned short* sA, unsigned short* sB,
                                             int tid, f32x4 (&acc)[4][4]) {
  const int lane = tid & 63, w = tid >> 6;
  const int wm = w >> 1, wn = w & 1, g = lane >> 4, lc = lane & 15;
  for (int kt = 0; kt < 1024; kt += 32) {
    __syncthreads();
#pragma unroll
    for (int s = 0; s < 2; ++s) {
      int c = s * 256 + tid;
      int row = c >> 2, ko = (c & 3) * 8;
      int lbase = (s * 256 + w * 64) * 8;
      gload16(&A[(size_t)(m0 + row) * 1024 + kt + ko], &sA[lbase]);
      gload16(&Bt[(size_t)(n0 + row) * 1024 + kt + ko], &sB[lbase]);
    }
    __syncthreads();
    bf16x8 af[4], bfr[4];
#pragma unroll
    for (int i = 0; i < 4; ++i) {
      af[i] = *(const bf16x8*)&sA[(wm * 64 + i * 16 + lc) * 32 + g * 8];
      bfr[i] = *(const bf16x8*)&sB[(wn * 64 + i * 16 + lc) * 32 + g * 8];
    }
#pragma unroll
    for (int mi = 0; mi < 4; ++mi)
#pragma unroll
      for (int ni = 0; ni < 4; ++ni)
        acc[mi][ni] = mfma16(af[mi], bfr[ni], acc[mi][ni]);
  }
}

// ---------------- all 4 projections in one launch ----------------
__global__ __launch_bounds__(256) void proj4_kernel(
    const unsigned short* __restrict__ hb, const unsigned short* __restrict__ rb,
    const unsigned short* __restrict__ wq_t, const unsigned short* __restrict__ wk_t,
    const unsigned short* __restrict__ wv_t, const unsigned short* __restrict__ wr_t,
    const float* __restrict__ rwb, const float* __restrict__ rrb, const float* __restrict__ rsb,
    unsigned short* __restrict__ qwb, unsigned short* __restrict__ qrb,
    unsigned short* __restrict__ qsb,
    unsigned short* __restrict__ khb, unsigned short* __restrict__ vhb,
    unsigned short* __restrict__ krhb) {
  __shared__ unsigned short sA[128 * 32];
  __shared__ unsigned short sB[128 * 32];
  const int bx = blockIdx.x;
  int sel, rblk;
  const unsigned short* A;
  if (bx < 384) { sel = bx >> 7; rblk = bx & 127; A = hb; }
  else { sel = 3; rblk = bx - 384; A = rb; }
  const unsigned short* Bt = sel == 0 ? wq_t : (sel == 1 ? wk_t : (sel == 2 ? wv_t : wr_t));
  const int n0 = (rblk & 7) * 128, m0 = (rblk >> 3) * 128;
  const int tid = threadIdx.x, lane = tid & 63, w = tid >> 6;
  const int wm = w >> 1, wn = w & 1, g = lane >> 4, lc = lane & 15;
  f32x4 acc[4][4] = {};
  gemm_core128(A, Bt, m0, n0, sA, sB, tid, acc);
#pragma unroll
  for (int ni = 0; ni < 4; ++ni) {
    int col = n0 + wn * 64 + ni * 16 + lc;
    float bw = 0.f, br = 0.f, bs = 0.f;
    if (sel == 0) { bw = rwb[col]; br = rrb[col]; bs = rsb[col]; }
#pragma unroll
    for (int mi = 0; mi < 4; ++mi) {
      int rowb = m0 + wm * 64 + mi * 16 + g * 4;
#pragma unroll
      for (int r = 0; r < 4; ++r) {
        float v = acc[mi][ni][r];
        size_t idx = (size_t)(rowb + r) * 1024 + col;
        if (sel == 0) {
          qwb[idx] = f2bf((v + bw) * 0.125f);
          qrb[idx] = f2bf((v + br) * 0.125f);
          qsb[idx] = f2bf((v + bs) * 0.125f);
        } else if (sel == 1) {
          khb[idx] = f2bf(v);
        } else if (sel == 2) {
          vhb[idx] = f2bf(v);
        } else {
          krhb[idx] = f2bf(v);
        }
      }
    }
  }
}

// ---------------- out-projection: BM=64 tile -> 256 blocks ----------------
__global__ __launch_bounds__(256) void gemm64_out(const unsigned short* __restrict__ A,
                                                  const unsigned short* __restrict__ Bt,
                                                  float* __restrict__ C) {
  __shared__ unsigned short sA[64 * 32];
  __shared__ unsigned short sB[128 * 32];
  const int tid = threadIdx.x, lane = tid & 63, w = tid >> 6;
  const int wm = w >> 1, wn = w & 1, g = lane >> 4, lc = lane & 15;
  const int m0 = blockIdx.y * 64, n0 = blockIdx.x * 128;
  f32x4 acc[2][4] = {};
  for (int kt = 0; kt < 1024; kt += 32) {
    __syncthreads();
    {
      int c = tid;  // A chunk
      gload16(&A[(size_t)(m0 + (c >> 2)) * 1024 + kt + (c & 3) * 8], &sA[w * 64 * 8]);
      gload16(&Bt[(size_t)(n0 + (c >> 2)) * 1024 + kt + (c & 3) * 8], &sB[w * 64 * 8]);
      int c2 = tid + 256;
      gload16(&Bt[(size_t)(n0 + (c2 >> 2)) * 1024 + kt + (c2 & 3) * 8], &sB[(256 + w * 64) * 8]);
    }
    __syncthreads();
    bf16x8 af[2], bfr[4];
#pragma unroll
    for (int i = 0; i < 2; ++i)
      af[i] = *(const bf16x8*)&sA[(wm * 32 + i * 16 + lc) * 32 + g * 8];
#pragma unroll
    for (int i = 0; i < 4; ++i)
      bfr[i] = *(const bf16x8*)&sB[(wn * 64 + i * 16 + lc) * 32 + g * 8];
#pragma unroll
    for (int mi = 0; mi < 2; ++mi)
#pragma unroll
      for (int ni = 0; ni < 4; ++ni)
        acc[mi][ni] = mfma16(af[mi], bfr[ni], acc[mi][ni]);
  }
#pragma unroll
  for (int ni = 0; ni < 4; ++ni) {
    int col = n0 + wn * 64 + ni * 16 + lc;
#pragma unroll
    for (int mi = 0; mi < 2; ++mi) {
      int rowb = m0 + wm * 32 + mi * 16 + g * 4;
#pragma unroll
      for (int r = 0; r < 4; ++r)
        C[(size_t)(rowb + r) * 1024 + col] = acc[mi][ni][r];
    }
  }
}

// ---------------- V transpose ----------------
__global__ __launch_bounds__(256) void transpose_v(const unsigned short* __restrict__ vh,
                                                   unsigned short* __restrict__ vT) {
  __shared__ unsigned short t[64][65];
  const int bn = blockIdx.y, j0 = blockIdx.x * 64;
  const int b = bn >> 4, n = bn & 15;
  const int r = threadIdx.x >> 4;
  const int c4 = (threadIdx.x & 15) * 4;
#pragma unroll
  for (int s = 0; s < 4; ++s) {
    int j = r + s * 16;
    us4 v = *(const us4*)&vh[((size_t)(j0 + j) * 2 + b) * 1024 + n * 64 + c4];
    t[j][c4 + 0] = v[0]; t[j][c4 + 1] = v[1]; t[j][c4 + 2] = v[2]; t[j][c4 + 3] = v[3];
  }
  __syncthreads();
#pragma unroll
  for (int s = 0; s < 4; ++s) {
    int d = r + s * 16;
    us4 v;
    v[0] = t[c4 + 0][d]; v[1] = t[c4 + 1][d]; v[2] = t[c4 + 2][d]; v[3] = t[c4 + 3][d];
    *(us4*)&vT[((size_t)bn * 64 + d) * 1024 + j0 + c4] = v;
  }
}

// ---------------- ef0/ef1 per (i,b,n) ----------------
__global__ __launch_bounds__(256) void ef_kernel(const unsigned short* __restrict__ qs,
                                                 const float* __restrict__ seg_embed,
                                                 float* __restrict__ ef0, float* __restrict__ ef1) {
  int gw = blockIdx.x * 4 + (threadIdx.x >> 6);
  int lane = threadIdx.x & 63;
  int n = gw & 15, ib = gw >> 4;
  int i = ib >> 1, b = ib & 1;
  float qv = bf2f(qs[(size_t)ib * 1024 + n * 64 + lane]);
  float p0 = qv * seg_embed[n * 64 + lane];
  float p1 = qv * seg_embed[1024 + n * 64 + lane];
#pragma unroll
  for (int m = 1; m < 64; m <<= 1) {
    p0 += __shfl_xor(p0, m);
    p1 += __shfl_xor(p1, m);
  }
  if (lane == 0) {
    ef0[(b * 16 + n) * 1024 + i] = p0;
    ef1[(b * 16 + n) * 1024 + i] = p1;
  }
}

// ---------------- fused relative attention: BI=128, 8 waves, j-split x2 ----------------
__global__ __launch_bounds__(512, 4) void attn_kernel(
    const unsigned short* __restrict__ qw, const unsigned short* __restrict__ qr,
    const unsigned short* __restrict__ kh, const unsigned short* __restrict__ krh,
    const unsigned short* __restrict__ vT,
    const float* __restrict__ ef0, const float* __restrict__ ef1,
    const unsigned int* __restrict__ segmask,
    float* __restrict__ part, float* __restrict__ ml) {
  __shared__ unsigned short sK[64][72];
  __shared__ unsigned short sVT[64][72];
  __shared__ unsigned short sKR[256][72];  // circular band, slot = jr & 255
  __shared__ unsigned short sP[8][16][80];

  const int tid = threadIdx.x, lane = tid & 63, w = tid >> 6;  // w: 0..7
  const int g = lane >> 4, lc = lane & 15;
  const int bn = blockIdx.x, b = bn >> 4, n = bn & 15;
  const int i0 = blockIdx.y * 128;
  const int js = blockIdx.z;
  const int S0 = 1024 + js * 512 - i0 - 127;

  bf16x8 fqw[2], fqr[2];
  const int qrow = i0 + w * 16 + lc;
#pragma unroll
  for (int ks = 0; ks < 2; ++ks) {
    size_t off = ((size_t)qrow * 2 + b) * 1024 + n * 64 + ks * 32 + g * 8;
    fqw[ks] = *(const bf16x8*)&qw[off];
    fqr[ks] = *(const bf16x8*)&qr[off];
  }
  float ef0v[4], dv[4];
  unsigned int smoff[4];
#pragma unroll
  for (int r = 0; r < 4; ++r) {
    int i = i0 + w * 16 + g * 4 + r;
    float e0 = ef0[bn * 1024 + i];
    ef0v[r] = e0;
    dv[r] = ef1[bn * 1024 + i] - e0;
    smoff[r] = ((unsigned)b << 20) | ((unsigned)i << 10) | (unsigned)lc;
  }
  float mrun[4], lsum[4];
  f32x4 accO[4] = {};
#pragma unroll
  for (int r = 0; r < 4; ++r) { mrun[r] = -3e38f; lsum[r] = 0.f; }

  const int srow = tid >> 3;       // 0..63
  const int sko = (tid & 7) * 8;   // short offset of 16B chunk

  // prologue: stage band rows [S0, S0+191]
#pragma unroll
  for (int pp = 0; pp < 3; ++pp) {
    int jr = S0 + pp * 64 + srow;
    *(uint4*)&sKR[jr & 255][sko] =
        *(const uint4*)&krh[((size_t)jr * 2 + b) * 1024 + n * 64 + sko];
  }
  // prefetch tile 0
  int j0 = js * 512;
  uint4 rK = *(const uint4*)&kh[((size_t)(j0 + srow) * 2 + b) * 1024 + n * 64 + sko];
  uint4 rV = *(const uint4*)&vT[((size_t)bn * 64 + srow) * 1024 + j0 + sko];
  uint4 rR = *(const uint4*)&krh[((size_t)(S0 + 192 + srow) * 2 + b) * 1024 + n * 64 + sko];

  for (int t = 0; t < 8; ++t) {
    j0 = (js * 8 + t) * 64;
    __syncthreads();  // previous tile's reads done
    *(uint4*)&sK[srow][sko] = rK;
    *(uint4*)&sVT[srow][sko] = rV;
    if (t < 7) {
      *(uint4*)&sKR[(S0 + 192 + t * 64 + srow) & 255][sko] = rR;
      int j0n = j0 + 64;
      rK = *(const uint4*)&kh[((size_t)(j0n + srow) * 2 + b) * 1024 + n * 64 + sko];
      rV = *(const uint4*)&vT[((size_t)bn * 64 + srow) * 1024 + j0n + sko];
      if (t < 6) {
        int jr = S0 + 256 + t * 64 + srow;
        if (jr > 2047) jr = 2047;
        rR = *(const uint4*)&krh[((size_t)jr * 2 + b) * 1024 + n * 64 + sko];
      }
    }
    // segmask loads in flight across the barrier
    unsigned int msv[4][4];
#pragma unroll
    for (int r = 0; r < 4; ++r)
#pragma unroll
      for (int nf = 0; nf < 4; ++nf)
        msv[r][nf] = segmask[smoff[r] + j0 + nf * 16];
    __syncthreads();

    // bd band MFMAs (own-wave 5 fragments)
    const int base = S0 + t * 64 + (7 - w) * 16;
    f32x4 bdk[5];
#pragma unroll
    for (int k = 0; k < 5; ++k) {
      f32x4 a = {0.f, 0.f, 0.f, 0.f};
#pragma unroll
      for (int ks = 0; ks < 2; ++ks) {
        bf16x8 fk = *(const bf16x8*)&sKR[(base + k * 16 + lc) & 255][ks * 32 + g * 8];
        a = mfma16(fqr[ks], fk, a);
      }
      bdk[k] = a;
    }
    // gather + segmask/ef baseline
    float p[4][4];
#pragma unroll
    for (int r = 0; r < 4; ++r) {
      const int a_ = g * 4 + r;
      const int srcl = (lane & 48) | ((lc + 15 - a_) & 15);
      float s0 = __shfl(bdk[0][r], srcl);
      float s1 = __shfl(bdk[1][r], srcl);
      float s2 = __shfl(bdk[2][r], srcl);
      float s3 = __shfl(bdk[3][r], srcl);
      float s4 = __shfl(bdk[4][r], srcl);
      const bool lo = lc <= a_;
#pragma unroll
      for (int nf = 0; nf < 4; ++nf) {
        unsigned int u = msv[r][nf];
        float sgv = bf2f((unsigned short)(u & 0xffffu));
        float mkv = bf2f((unsigned short)(u >> 16));
        float bdv = lo ? (nf == 0 ? s0 : nf == 1 ? s1 : nf == 2 ? s2 : s3)
                       : (nf == 0 ? s1 : nf == 1 ? s2 : nf == 2 ? s3 : s4);
        p[r][nf] = ef0v[r] + sgv * dv[r] + mkv + bdv;
      }
    }
    // ac MFMAs
    f32x4 aa[4];
#pragma unroll
    for (int nf = 0; nf < 4; ++nf) {
      f32x4 a = {0.f, 0.f, 0.f, 0.f};
#pragma unroll
      for (int ks = 0; ks < 2; ++ks) {
        bf16x8 fk = *(const bf16x8*)&sK[nf * 16 + lc][ks * 32 + g * 8];
        a = mfma16(fqw[ks], fk, a);
      }
      aa[nf] = a;
    }
#pragma unroll
    for (int r = 0; r < 4; ++r)
#pragma unroll
      for (int nf = 0; nf < 4; ++nf) p[r][nf] += aa[nf][r];

    // online softmax (DPP reduces, VALU pipe)
#pragma unroll
    for (int r = 0; r < 4; ++r) {
      float mt = fmaxf(fmaxf(p[r][0], p[r][1]), fmaxf(p[r][2], p[r][3]));
      mt = rmax16(mt);
      float mnew = fmaxf(mrun[r], mt);
      float corr = __expf(mrun[r] - mnew);
      mrun[r] = mnew;
      float se = 0.f;
#pragma unroll
      for (int nf = 0; nf < 4; ++nf) {
        float e = __expf(p[r][nf] - mnew);
        p[r][nf] = e;
        se += e;
      }
      se = rsum16(se);
      lsum[r] = lsum[r] * corr + se;
#pragma unroll
      for (int df = 0; df < 4; ++df) accO[df][r] *= corr;
#pragma unroll
      for (int nf = 0; nf < 4; ++nf)
        sP[w][g * 4 + r][nf * 16 + lc] = f2bf(p[r][nf]);
    }
    // pv accumulate
#pragma unroll
    for (int ks = 0; ks < 2; ++ks) {
      bf16x8 fp = *(const bf16x8*)&sP[w][lc][ks * 32 + g * 8];
#pragma unroll
      for (int df = 0; df < 4; ++df) {
        bf16x8 fv = *(const bf16x8*)&sVT[df * 16 + lc][ks * 32 + g * 8];
        accO[df] = mfma16(fp, fv, accO[df]);
      }
    }
  }
  // write split partials
#pragma unroll
  for (int r = 0; r < 4; ++r) {
    int i = i0 + w * 16 + g * 4 + r;
    size_t pb = ((size_t)(js * 32 + bn) * 1024 + i) * 64;
#pragma unroll
    for (int df = 0; df < 4; ++df) part[pb + df * 16 + lc] = accO[df][r];
    if (lc == 0) {
      size_t mb = (((size_t)js * 32 + bn) * 1024 + i) * 2;
      ml[mb] = mrun[r];
      ml[mb + 1] = lsum[r];
    }
  }
}

// ---------------- combine the two j-splits ----------------
__global__ __launch_bounds__(256) void combine_kernel(const float* __restrict__ part,
                                                      const float* __restrict__ ml,
                                                      unsigned short* __restrict__ av) {
  int gw = blockIdx.x * 4 + (threadIdx.x >> 6);
  int lane = threadIdx.x & 63;
  int bn = gw >> 10, i = gw & 1023;
  int b = bn >> 4, n = bn & 15;
  float m0 = ml[((size_t)bn * 1024 + i) * 2];
  float l0 = ml[((size_t)bn * 1024 + i) * 2 + 1];
  float m1 = ml[(((size_t)32 + bn) * 1024 + i) * 2];
  float l1 = ml[(((size_t)32 + bn) * 1024 + i) * 2 + 1];
  float mx = fmaxf(m0, m1);
  float w0 = __expf(m0 - mx), w1 = __expf(m1 - mx);
  float inv = 1.f / (l0 * w0 + l1 * w1);
  float o = part[((size_t)bn * 1024 + i) * 64 + lane] * w0 +
            part[(((size_t)32 + bn) * 1024 + i) * 64 + lane] * w1;
  av[((size_t)i * 2 + b) * 1024 + n * 64 + lane] = f2bf(o * inv);
}

// ---------------- residual + LayerNorm ----------------
__global__ __launch_bounds__(256) void ln_kernel(const float* __restrict__ gout,
                                                 const float* __restrict__ h,
                                                 const float* __restrict__ gamma,
                                                 const float* __restrict__ beta,
                                                 float* __restrict__ out) {
  __shared__ float red[8];
  const int row = blockIdx.x;
  const int tid = threadIdx.x;
  float x[4];
  float s = 0.f;
#pragma unroll
  for (int q = 0; q < 4; ++q) {
    int d = tid + q * 256;
    x[q] = gout[(size_t)row * 1024 + d] + h[(size_t)row * 1024 + d];
    s += x[q];
  }
#pragma unroll
  for (int m = 1; m < 64; m <<= 1) s += __shfl_xor(s, m);
  if ((tid & 63) == 0) red[tid >> 6] = s;
  __syncthreads();
  s = red[0] + red[1] + red[2] + red[3];
  float mu = s * (1.f / 1024.f);
  float v = 0.f;
#pragma unroll
  for (int q = 0; q < 4; ++q) {
    float dd = x[q] - mu;
    v += dd * dd;
  }
#pragma unroll
  for (int m = 1; m < 64; m <<= 1) v += __shfl_xor(v, m);
  if ((tid & 63) == 0) red[4 + (tid >> 6)] = v;
  __syncthreads();
  v = red[4] + red[5] + red[6] + red[7];
  float rstd = rsqrtf(v * (1.f / 1024.f) + 1e-12f);
#pragma unroll
  for (int q = 0; q < 4; ++q) {
    int d = tid + q * 256;
    out[(size_t)row * 1024 + d] = (x[q] - mu) * rstd * gamma[d] + beta[d];
  }
}

extern "C" void kernel_launch(void* const* d_in, const int* in_sizes, int n_in,
                              void* d_out, int out_size, void* d_ws, size_t ws_size,
                              hipStream_t stream) {
  const float* h = (const float*)d_in[0];
  const float* r = (const float*)d_in[1];
  const unsigned char* seg = (const unsigned char*)d_in[2];
  const float* mask = (const float*)d_in[3];
  const float* wq = (const float*)d_in[4];
  const float* wk = (const float*)d_in[5];
  const float* wv = (const float*)d_in[6];
  const float* wr = (const float*)d_in[7];
  const float* wo = (const float*)d_in[8];
  const float* rwb = (const float*)d_in[9];
  const float* rrb = (const float*)d_in[10];
  const float* rsb = (const float*)d_in[11];
  const float* seg_embed = (const float*)d_in[12];
  const float* gamma = (const float*)d_in[13];
  const float* beta = (const float*)d_in[14];
  float* out = (float*)d_out;

  char* ws = (char*)d_ws;
  size_t off = 0;
  auto alloc = [&](size_t bytes) {
    size_t cur = off;
    off = (off + bytes + 255) & ~(size_t)255;
    return cur;
  };
  unsigned short* hb = (unsigned short*)(ws + alloc(2048 * 1024 * 2));
  unsigned short* rb = (unsigned short*)(ws + alloc(4096 * 1024 * 2));
  unsigned short* wq_t = (unsigned short*)(ws + alloc(1024 * 1024 * 2));
  unsigned short* wk_t = (unsigned short*)(ws + alloc(1024 * 1024 * 2));
  unsigned short* wv_t = (unsigned short*)(ws + alloc(1024 * 1024 * 2));
  unsigned short* wr_t = (unsigned short*)(ws + alloc(1024 * 1024 * 2));
  unsigned short* wo_b = (unsigned short*)(ws + alloc(1024 * 1024 * 2));
  unsigned short* qwb = (unsigned short*)(ws + alloc(2048 * 1024 * 2));
  unsigned short* qrb = (unsigned short*)(ws + alloc(2048 * 1024 * 2));
  unsigned short* qsb = (unsigned short*)(ws + alloc(2048 * 1024 * 2));
  unsigned short* khb = (unsigned short*)(ws + alloc(2048 * 1024 * 2));
  unsigned short* vhb = (unsigned short*)(ws + alloc(2048 * 1024 * 2));
  unsigned short* krhb = (unsigned short*)(ws + alloc(4096 * 1024 * 2));
  unsigned short* vTb = (unsigned short*)(ws + alloc(2048 * 1024 * 2));
  float* ef0 = (float*)(ws + alloc(2048 * 16 * 4));
  float* ef1 = (float*)(ws + alloc(2048 * 16 * 4));
  unsigned int* segmask = (unsigned int*)(ws + alloc(2 * 1024 * 1024 * 4));
  unsigned short* avb = (unsigned short*)(ws + alloc(2048 * 1024 * 2));
  float* gout = (float*)(ws + alloc(2048 * 1024 * 4));
  float* part = (float*)(ws + alloc((size_t)2 * 32 * 1024 * 64 * 4));
  float* mlb = (float*)(ws + alloc((size_t)2 * 32 * 1024 * 2 * 4));
  (void)ws_size; (void)in_sizes; (void)n_in; (void)out_size;

  cast3_kernel<<<7168, 256, 0, stream>>>(h, r, wo, hb, rb, wo_b);
  transpose_cast4<<<dim3(32, 32, 4), 256, 0, stream>>>(wq, wk, wv, wr, wq_t, wk_t, wv_t, wr_t);
  segmask_kernel<<<4096, 256, 0, stream>>>(seg, mask, segmask);

  proj4_kernel<<<640, 256, 0, stream>>>(hb, rb, wq_t, wk_t, wv_t, wr_t, rwb, rrb, rsb,
                                        qwb, qrb, qsb, khb, vhb, krhb);

  transpose_v<<<dim3(16, 32), 256, 0, stream>>>(vhb, vTb);
  ef_kernel<<<8192, 256, 0, stream>>>(qsb, seg_embed, ef0, ef1);

  attn_kernel<<<dim3(32, 8, 2), 512, 0, stream>>>(qwb, qrb, khb, krhb, vTb,
                                                  ef0, ef1, segmask, part, mlb);
  combine_kernel<<<8192, 256, 0, stream>>>(part, mlb, avb);

  gemm64_out<<<dim3(8, 32), 256, 0, stream>>>(avb, wo_b, gout);
  ln_kernel<<<2048, 256, 0, stream>>>(gout, h, gamma, beta, out);
}